// Round 11
// baseline (570.134 us; speedup 1.0000x reference)
//
#include <hip/hip_runtime.h>
#include <hip/hip_cooperative_groups.h>

namespace cg = cooperative_groups;

typedef __attribute__((ext_vector_type(8))) short bf16x8;
typedef __attribute__((ext_vector_type(4))) float f32x4;
typedef __attribute__((ext_vector_type(2))) unsigned int u32x2;
typedef __attribute__((ext_vector_type(4))) unsigned int u32x4;
typedef __attribute__((ext_vector_type(2))) __bf16 bf16x2t;
typedef unsigned short u16;
typedef unsigned int u32;
typedef unsigned long long u64;

#define DI __device__ __forceinline__

// Problem constants: B=8, A=1024, NB=64, NAB=NF=128, NG=25, NI=3
#define NKNOT 2048

DI float b2f(u16 u){ union{u32 i; float f;} v; v.i = ((u32)u)<<16; return v.f; }
DI float asf(u32 u){ union{u32 i; float f;} v; v.i = u; return v.f; }
DI u16 f2b(float f){ union{float f; u32 i;} v; v.f=f; u32 u=v.i;
                     return (u16)((u + 0x7fffu + ((u>>16)&1u))>>16); }
DI u32 pk2(float lo, float hi){
#if __has_builtin(__builtin_amdgcn_cvt_pk_bf16_f32)
  bf16x2t h = __builtin_amdgcn_cvt_pk_bf16_f32(lo, hi);
  u32 d; __builtin_memcpy(&d, &h, 4); return d;
#else
  return (u32)f2b(lo) | ((u32)f2b(hi)<<16);
#endif
}
DI float fexp2(float x){
#if __has_builtin(__builtin_amdgcn_exp2f)
  return __builtin_amdgcn_exp2f(x);
#else
  return __expf(x*0.6931471805599453f);
#endif
}
DI float flog2(float x){
#if __has_builtin(__builtin_amdgcn_logf)
  return __builtin_amdgcn_logf(x);
#else
  return __logf(x)*1.4426950408889634f;
#endif
}
DI float ldin(const void* p, size_t i, int isbf){
  return isbf ? b2f(((const u16*)p)[i]) : ((const float*)p)[i];
}
DI f32x4 ldin4(const void* p, size_t i, int isbf){
  if(isbf){
    u32x2 d = *(const u32x2*)((const u16*)p + i);
    f32x4 r;
    r[0] = b2f((u16)(d[0]&0xffff)); r[1] = b2f((u16)(d[0]>>16));
    r[2] = b2f((u16)(d[1]&0xffff)); r[3] = b2f((u16)(d[1]>>16));
    return r;
  }
  return *(const f32x4*)((const float*)p + i);
}
DI int probe_bf(const void* nmask){ return ((const u16*)nmask)[0] == 0x3F80u; }

DI f32x4 mfma16(bf16x8 a, bf16x8 b, f32x4 c){
  return __builtin_amdgcn_mfma_f32_16x16x32_bf16(a,b,c,0,0,0);
}
DI bf16x8 ldfragA_f32(const float* p){
  f32x4 a = ((const f32x4*)p)[0], b = ((const f32x4*)p)[1];
  union{ u32 d[4]; bf16x8 v; } u;
  u.d[0]=pk2(a[0],a[1]); u.d[1]=pk2(a[2],a[3]);
  u.d[2]=pk2(b[0],b[1]); u.d[3]=pk2(b[2],b[3]);
  return u.v;
}
DI float sspf(float x){ return __logf(1.f + __expf(x)) - 0.6931471805599453f; }

// WF layout per interaction (u16 offsets; frag = 512 u16):
//   fw1   frags 0..7     off 0      (K=32: rows 0..24 = fw1*log2e, 25 = fb1*log2e)
//   fw2   frags 8..47    off 4096   (kk 0..4; kk=4 row k=128 = fb2)
//   in2f  frags 48..79   off 24576
//   f2o   frags 80..111  off 40960
//   dense frags 112..143 off 57344
#define WF_STRIDE 73728
#define WF_FW2    4096
#define WF_IN2F   24576
#define WF_F2O    40960
#define WF_DEN    57344

// ---------------------------------------------------------------------------
// Fused setup: blocks [0,1024) embed (f32x4) | [1024,3072) dist->desc
// (ballot-compacted per atom + CNT) | [3072,3180) wfrag (144 frags/interaction)
__global__ __launch_bounds__(256) void k_setup(const void* __restrict__ pos,
                                               const void* __restrict__ cell,
                                               const void* __restrict__ cello,
                                               const void* __restrict__ nmask,
                                               const void* __restrict__ emb,
                                               const void* __restrict__ fw1,
                                               const void* __restrict__ fb1,
                                               const void* __restrict__ fw2,
                                               const void* __restrict__ fb2,
                                               const void* __restrict__ in2f,
                                               const void* __restrict__ f2o,
                                               const void* __restrict__ den,
                                               const int* __restrict__ z,
                                               const int* __restrict__ nbrs,
                                               float* __restrict__ X,
                                               u32x2* __restrict__ DESC,
                                               u32* __restrict__ CNT,
                                               u16* __restrict__ WF){
  int isbf = probe_bf(nmask);
  int bx = blockIdx.x, tid = threadIdx.x;
  if(bx < 1024){
    int idx = bx*256 + tid;                    // < 8192*32
    int a = idx>>5, f4 = (idx&31)*4;
    f32x4 e = ldin4(emb, (size_t)z[a]*128 + f4, isbf);
    *(f32x4*)(X + (size_t)a*128 + f4) = e;
    return;
  }
  if(bx < 3072){
    int pairIdx = (bx-1024)*256 + tid;         // < 8192*64
    int atom = pairIdx>>6;
    int lane = tid & 63;                       // pair index within atom
    int b = atom>>10;
    int nb = nbrs[pairIdx];
    int jrow = (b<<10) + nb;
    float pi0=ldin(pos,atom*3+0,isbf), pi1=ldin(pos,atom*3+1,isbf), pi2=ldin(pos,atom*3+2,isbf);
    float pj0=ldin(pos,jrow*3+0,isbf), pj1=ldin(pos,jrow*3+1,isbf), pj2=ldin(pos,jrow*3+2,isbf);
    float co0=ldin(cello,(size_t)pairIdx*3+0,isbf),
          co1=ldin(cello,(size_t)pairIdx*3+1,isbf),
          co2=ldin(cello,(size_t)pairIdx*3+2,isbf);
    size_t cb = (size_t)b*9;
    pj0 += co0*ldin(cell,cb+0,isbf) + co1*ldin(cell,cb+3,isbf) + co2*ldin(cell,cb+6,isbf);
    pj1 += co0*ldin(cell,cb+1,isbf) + co1*ldin(cell,cb+4,isbf) + co2*ldin(cell,cb+7,isbf);
    pj2 += co0*ldin(cell,cb+2,isbf) + co1*ldin(cell,cb+5,isbf) + co2*ldin(cell,cb+8,isbf);
    float d0 = pj0-pi0, d1 = pj1-pi1, d2 = pj2-pi2;
    float dd = d0*d0 + d1*d1 + d2*d2;
    float m  = ldin(nmask,pairIdx,isbf);
    float r  = sqrtf(m>0.f ? dd : 1.f) * m;
    float c  = 0.5f*(__cosf(r*3.14159265358979f/5.f)+1.f) * ((r<5.f)?1.f:0.f) * m;
    float s  = r * ((float)(NKNOT-1)/5.0f);
    int   k  = (int)s; if(k > NKNOT-2) k = NKNOT-2;
    float fr = s - (float)k;
    float a0 = c*(1.f-fr), a1 = c*fr;
    union{ _Float16 h[2]; u32 u; } pa;
    pa.h[0] = (_Float16)a0; pa.h[1] = (_Float16)a1;
    // ballot-compact: active pairs -> [0,cnt), zero-descs -> [cnt,64)
    int act = (c > 0.f);
    u64 bal = __ballot(act);
    u64 below = bal & ((1ULL<<lane)-1ULL);
    int cnt = (int)__popcll(bal);
    int apre = (int)__popcll(below);
    int pos_ = act ? apre : (cnt + (lane - apre));
    u32x2 dsc;
    if(act){ dsc[0] = pa.u; dsc[1] = (u32)k | ((u32)nb<<16); }
    else   { dsc[0] = 0u;   dsc[1] = 0u; }
    DESC[(size_t)atom*64 + pos_] = dsc;
    if(lane == 0) CNT[atom] = (u32)cnt;
    return;
  }
  // weight fragments: wid in [0,432) = 3 interactions x 144 frags
  int wid = (bx-3072)*4 + (tid>>6);
  int lane = tid & 63;
  int q = lane>>4, l15 = lane&15;
  int i = wid/144, r = wid%144;
  int mat, kk, t;
  if(r < 8){ mat=0; kk=0; t=r; }
  else if(r < 48){ int r2 = r-8; mat=1; kk=r2>>3; t=r2&7; }
  else { int r3 = r-48; mat = 2 + (r3>>5); kk = (r3>>3)&3; t = r3&7; }
  const void* src; size_t sbase; int K; int off;
  switch(mat){
    case 0:  src = fw1;  sbase=(size_t)i*3200;  K=25;  off=0;       break;
    case 1:  src = fw2;  sbase=(size_t)i*16384; K=128; off=WF_FW2;  break;
    case 2:  src = in2f; sbase=(size_t)i*16384; K=128; off=WF_IN2F; break;
    case 3:  src = f2o;  sbase=(size_t)i*16384; K=128; off=WF_F2O;  break;
    default: src = den;  sbase=(size_t)i*16384; K=128; off=WF_DEN;  break;
  }
  int c = t*16 + l15;
  bf16x8 frag;
  #pragma unroll
  for(int j=0;j<8;j++){
    int k = kk*32 + q*8 + j;
    float v;
    if(k < K)                 v = ldin(src, sbase + (size_t)k*128 + c, isbf);
    else if(mat==0 && k==25)  v = ldin(fb1, (size_t)i*128 + c, isbf);   // fb1 row
    else if(mat==1 && k==128) v = ldin(fb2, (size_t)i*128 + c, isbf);   // fb2 row
    else                      v = 0.f;
    if(mat==0) v *= 1.4426950408889634f;       // log2e pre-scale (exp2 domain)
    frag[j] = (short)f2b(v);
  }
  *(bf16x8*)(WF + (size_t)i*WF_STRIDE + off + ((kk*8+t)*64 + lane)*8) = frag;
}

// ---------------------------------------------------------------------------
// Shared device helpers for table / proj / iter bodies (used by k_mid/k_iter
// fallbacks AND by the cooperative k_coop).

// table: one wave computes 16 knot rows of TT[i] from WF fw1/fw2 frags.
DI void table_wave(const u16* __restrict__ WF, u32x2* __restrict__ TT,
                   int wid, int lane, u16 (*H)[168]){
  int q = lane>>4, l15 = lane&15;
  int i  = wid>>7;
  int kb = (wid&127)*16;
  const u16* fw1f = WF + (size_t)i*WF_STRIDE;
  const u16* fw2f = WF + (size_t)i*WF_STRIDE + WF_FW2;

  const float width = 5.0f/24.0f;
  const float c2 = (-0.5f/(width*width))*1.4426950408889634f;
  float r = (float)(kb + l15) * (5.0f/(float)(NKNOT-1));

  float gv[8];
  #pragma unroll
  for(int j=0;j<8;j++){
    int k = q*8+j;
    if(k < 25){ float t = fmaf(-width,(float)k,r); gv[j] = fexp2(c2*t*t); }
    else gv[j] = (k==25) ? 1.f : 0.f;
  }
  union{ u32 d[4]; bf16x8 v; } afu;
  afu.d[0]=pk2(gv[0],gv[1]); afu.d[1]=pk2(gv[2],gv[3]);
  afu.d[2]=pk2(gv[4],gv[5]); afu.d[3]=pk2(gv[6],gv[7]);
  bf16x8 af = afu.v;

  f32x4 acc[8];
  #pragma unroll
  for(int t=0;t<8;t++){
    bf16x8 w1 = *(const bf16x8*)(fw1f + (size_t)t*512 + lane*8);
    acc[t] = mfma16(w1, af, (f32x4){0.f,0.f,0.f,0.f});
  }
  const float ln2 = 0.69314718055994531f;
  #pragma unroll
  for(int t=0;t<8;t++){
    float h0 = fmaf(flog2(1.f+fexp2(acc[t][0])), ln2, -ln2);
    float h1 = fmaf(flog2(1.f+fexp2(acc[t][1])), ln2, -ln2);
    float h2 = fmaf(flog2(1.f+fexp2(acc[t][2])), ln2, -ln2);
    float h3 = fmaf(flog2(1.f+fexp2(acc[t][3])), ln2, -ln2);
    u32x2 d; d[0]=pk2(h0,h1); d[1]=pk2(h2,h3);
    *(u32x2*)(&H[l15][t*16 + q*4]) = d;
  }
  { // bias block cols 128..159: col128 = 1.0 (adds fb2), rest 0
    u32x2 zb; zb[0] = (q==0) ? pk2(1.f, 0.f) : 0u; zb[1] = 0u;
    *(u32x2*)(&H[l15][128 + q*4]) = zb;
    u32x2 zz; zz[0]=0u; zz[1]=0u;
    *(u32x2*)(&H[l15][144 + q*4]) = zz;
  }
  #pragma unroll
  for(int t=0;t<8;t++) acc[t] = (f32x4){0.f,0.f,0.f,0.f};
  #pragma unroll
  for(int kk=0;kk<5;kk++){
    bf16x8 a2 = *(const bf16x8*)(&H[l15][kk*32 + q*8]);
    #pragma unroll
    for(int t=0;t<8;t++){
      bf16x8 wv = *(const bf16x8*)(fw2f + ((kk*8+t)*64 + lane)*8);
      acc[t] = mfma16(a2, wv, acc[t]);
    }
  }
  // store interleaved: row -> TT[row].slot0, TT[row-1].slot1
  u32x2* ttb = TT + (size_t)i*NKNOT*64;
  int row = kb + l15;
  #pragma unroll
  for(int t=0;t<8;t++){
    u32 d0 = pk2(acc[t][0],acc[t][1]);
    u32 d1 = pk2(acc[t][2],acc[t][3]);
    int l = t*8 + q*2;
    ((u32*)&ttb[(size_t)row*64 + l    ])[0] = d0;
    ((u32*)&ttb[(size_t)row*64 + l + 1])[0] = d1;
    if(row > 0){
      ((u32*)&ttb[(size_t)(row-1)*64 + l    ])[1] = d0;
      ((u32*)&ttb[(size_t)(row-1)*64 + l + 1])[1] = d1;
    }
  }
}

// proj: one wave computes 16 rows of Y = X @ in2f[0] from WF frags.
DI void proj_wave(const u16* __restrict__ WF, const float* __restrict__ X,
                  float* __restrict__ Y, int wid2, int lane){
  int q = lane>>4, l15 = lane&15;
  int row0 = wid2*16;
  const u16* wf = WF + WF_IN2F;
  f32x4 acc[8];
  #pragma unroll
  for(int t=0;t<8;t++) acc[t] = (f32x4){0.f,0.f,0.f,0.f};
  #pragma unroll
  for(int kk=0;kk<4;kk++){
    bf16x8 xf = ldfragA_f32(X + (size_t)(row0+l15)*128 + kk*32 + q*8);
    #pragma unroll
    for(int t=0;t<8;t++){
      bf16x8 wv = *(const bf16x8*)(wf + ((kk*8+t)*64 + lane)*8);
      acc[t] = mfma16(wv, xf, acc[t]);
    }
  }
  #pragma unroll
  for(int t=0;t<8;t++)
    *(f32x4*)(Y + (size_t)(row0+l15)*128 + t*16 + q*4) = acc[t];
}

// iter body: one block (512 thr) processes 8 atoms for interaction iidx.
DI void iter_body(const u32x2* __restrict__ desc, const u32* __restrict__ CNT,
                  const u32x2* __restrict__ TT, const float* __restrict__ Yr,
                  float* __restrict__ X, float* __restrict__ Yw,
                  const u16* __restrict__ f2of, const u16* __restrict__ denf,
                  const u16* __restrict__ in2fN,
                  const void* __restrict__ f2ob, const void* __restrict__ denb,
                  void* __restrict__ OUT, int last, int iidx, int isbf,
                  int bid, int widx, int lane,
                  float (*AGGs)[132], u16 (*Tb)[136], u16 (*Xw)[136]){
  int q = lane>>4, l15 = lane&15;
  int row0 = (bid & 7)*1024 + (bid >> 3)*8;   // 8 atoms/block, batch = bid%8

  // ---- Phase 1: CFConv over active pairs, half-wave per pair.
  {
    int atom = row0 + widx;
    int cnt = (int)__builtin_amdgcn_readfirstlane(CNT[atom]);
    int ng  = (cnt + 3) >> 2;                    // chunks of 4 pairs
    u32x2 dsc = desc[(size_t)atom*64 + lane];    // lane p holds desc of slot p
    const char* Yb = (const char*)(Yr + (size_t)(atom & ~1023)*128);
    const char* Tc = (const char*)TT;
    int h   = lane>>5;                            // half index: pair parity
    int j32 = lane&31;                            // filters 4*j32 .. 4*j32+3
    int boff = j32<<4;                            // 16 B per lane
    f32x4 acc4 = (f32x4){0.f,0.f,0.f,0.f};
    #pragma unroll 1
    for(int g=0; g<ng; ++g){                      // 4 pairs per g (2 load steps)
      u32 cu[2]; u32x4 tt[2]; f32x4 yv[2];
      #pragma unroll
      for(int s=0; s<2; ++s){
        int p0 = g*4 + s*2;
        u32 d1a = __builtin_amdgcn_readlane(dsc[1], p0);
        u32 d1b = __builtin_amdgcn_readlane(dsc[1], p0+1);
        u32 d0a = __builtin_amdgcn_readlane(dsc[0], p0);
        u32 d0b = __builtin_amdgcn_readlane(dsc[0], p0+1);
        u32 d1 = h ? d1b : d1a;
        cu[s]  = h ? d0b : d0a;
        u32 krow = d1 & 0xffffu;
        u32 nbr  = d1 >> 16;
        tt[s] = *(const u32x4*)(Tc + ((size_t)krow<<9) + boff);
        yv[s] = *(const f32x4*)(Yb + ((size_t)nbr<<9) + boff);
      }
      #pragma unroll
      for(int s=0; s<2; ++s){
        union{ u32 u; _Float16 hh[2]; } pa; pa.u = cu[s];
        float a0 = (float)pa.hh[0], a1 = (float)pa.hh[1];
        float w0 = fmaf(a1, asf(tt[s][1]<<16),          a0*asf(tt[s][0]<<16));
        float w1 = fmaf(a1, asf(tt[s][1]&0xffff0000u),  a0*asf(tt[s][0]&0xffff0000u));
        float w2 = fmaf(a1, asf(tt[s][3]<<16),          a0*asf(tt[s][2]<<16));
        float w3 = fmaf(a1, asf(tt[s][3]&0xffff0000u),  a0*asf(tt[s][2]&0xffff0000u));
        acc4[0] = fmaf(w0, yv[s][0], acc4[0]);
        acc4[1] = fmaf(w1, yv[s][1], acc4[1]);
        acc4[2] = fmaf(w2, yv[s][2], acc4[2]);
        acc4[3] = fmaf(w3, yv[s][3], acc4[3]);
      }
    }
    *(f32x4*)(&AGGs[widx + 8*h][j32*4]) = acc4;   // partials: rows a / a+8
  }
  __syncthreads();

  // ---- Phase 2: v = ssp(agg @ f2out + b); t = widx; merge halves via shfl.
  {
    int t = widx;
    f32x4 acc = (f32x4){0.f,0.f,0.f,0.f};
    #pragma unroll
    for(int kk=0;kk<4;kk++){
      bf16x8 gf = ldfragA_f32(&AGGs[l15][kk*32 + q*8]);
      bf16x8 wv = *(const bf16x8*)(f2of + ((kk*8+t)*64 + lane)*8);
      acc = mfma16(wv, gf, acc);
    }
    #pragma unroll
    for(int r=0;r<4;r++) acc[r] += __shfl_xor(acc[r], 8);
    f32x4 bv = ldin4(f2ob, (size_t)iidx*128 + t*16 + q*4, isbf);
    u32x2 d;
    d[0] = pk2(sspf(acc[0]+bv[0]), sspf(acc[1]+bv[1]));
    d[1] = pk2(sspf(acc[2]+bv[2]), sspf(acc[3]+bv[3]));
    *(u32x2*)(&Tb[l15][t*16 + q*4]) = d;   // rows 8-15 duplicate rows 0-7
  }
  __syncthreads();

  // ---- Phase 2b: dense @ + bias + X residual; stores guarded to l15<8.
  {
    int t = widx;
    f32x4 acc = (f32x4){0.f,0.f,0.f,0.f};
    #pragma unroll
    for(int kk=0;kk<4;kk++){
      bf16x8 tf = *(const bf16x8*)(&Tb[l15][kk*32 + q*8]);
      bf16x8 wv = *(const bf16x8*)(denf + ((kk*8+t)*64 + lane)*8);
      acc = mfma16(wv, tf, acc);
    }
    size_t idx = (size_t)(row0+l15)*128 + t*16 + q*4;
    f32x4 bv = ldin4(denb, (size_t)iidx*128 + t*16 + q*4, isbf);
    f32x4 xv = *(const f32x4*)(X + idx);
    f32x4 xn;
    #pragma unroll
    for(int r=0;r<4;r++) xn[r] = xv[r] + acc[r] + bv[r];
    if(l15 < 8){
      *(f32x4*)(X + idx) = xn;
      if(last){
        if(isbf){
          u32x2 o; o[0]=pk2(xn[0],xn[1]); o[1]=pk2(xn[2],xn[3]);
          *(u32x2*)((u16*)OUT + idx) = o;
        } else {
          *(f32x4*)((float*)OUT + idx) = xn;
        }
      }
    }
    if(!last){
      u32x2 d; d[0]=pk2(xn[0],xn[1]); d[1]=pk2(xn[2],xn[3]);
      *(u32x2*)(&Xw[l15][t*16 + q*4]) = d;
    }
  }
  if(!last){
    __syncthreads();
    // ---- Phase 3: y_next = x_new @ in2f_next (other Y buffer); l15<8 stores.
    {
      int t = widx;
      f32x4 acc = (f32x4){0.f,0.f,0.f,0.f};
      #pragma unroll
      for(int kk=0;kk<4;kk++){
        bf16x8 xf = *(const bf16x8*)(&Xw[l15][kk*32 + q*8]);
        bf16x8 wv = *(const bf16x8*)(in2fN + ((kk*8+t)*64 + lane)*8);
        acc = mfma16(wv, xf, acc);
      }
      if(l15 < 8)
        *(f32x4*)(Yw + (size_t)(row0+l15)*128 + t*16 + q*4) = acc;
    }
  }
}

// ---------------------------------------------------------------------------
// Cooperative 3-in-1: phase A (table 128 blk x 3 waves + proj 64 blk x 8 waves)
// -> grid.sync -> iter0 -> grid.sync -> iter1 -> grid.sync -> iter2.
// 1024 blocks x 512 thr = 4 blocks/CU exactly; LDS 33280 B -> 4/CU fits.
__global__ __launch_bounds__(512, 8) void k_coop(const u32x2* __restrict__ desc,
                                                 const u32* __restrict__ CNT,
                                                 u32x2* __restrict__ TT,
                                                 float* __restrict__ Y,
                                                 float* __restrict__ Y2,
                                                 float* __restrict__ X,
                                                 const u16* __restrict__ WF,
                                                 const void* __restrict__ f2ob,
                                                 const void* __restrict__ denb,
                                                 const void* __restrict__ nmask,
                                                 void* __restrict__ OUT){
  __shared__ __align__(16) float AGGs[16][132];
  __shared__ __align__(16) u16 Tb[16][136];
  __shared__ __align__(16) u16 Xw[16][136];
  __shared__ __align__(16) u16 Hb[3][16][168];
  cg::grid_group grid = cg::this_grid();
  int isbf = probe_bf(nmask);
  int bid = blockIdx.x;
  int widx = threadIdx.x>>6;
  int lane = threadIdx.x & 63;

  // ---- Phase A: table + proj
  if(bid < 128){
    if(widx < 3) table_wave(WF, TT, bid*3 + widx, lane, Hb[widx]);
  } else if(bid < 192){
    proj_wave(WF, X, Y, (bid-128)*8 + widx, lane);
  }
  grid.sync();

  // ---- 3 interactions with grid-wide sync between
  #pragma unroll 1
  for(int it=0; it<3; ++it){
    const float* Yr = (it&1) ? Y2 : Y;
    float*       Yw = (it&1) ? Y  : Y2;
    const u16* base = WF + (size_t)it*WF_STRIDE;
    const u16* in2fN = (it<2) ? (WF + (size_t)(it+1)*WF_STRIDE + WF_IN2F) : WF;
    iter_body(desc, CNT, TT + (size_t)it*NKNOT*64, Yr, X, Yw,
              base + WF_F2O, base + WF_DEN, in2fN,
              f2ob, denb, OUT, (it==2)?1:0, it, isbf,
              bid, widx, lane, AGGs, Tb, Xw);
    if(it < 2) grid.sync();
  }
}

// ---------------------------------------------------------------------------
// Fallback kernels (used only if cooperative launch is rejected): exact R8 path.
__global__ __launch_bounds__(256) void k_mid(const u16* __restrict__ WF,
                                             u32x2* __restrict__ TT,
                                             const float* __restrict__ X,
                                             float* __restrict__ Y){
  __shared__ __align__(16) u16 Hb[4][16][168];
  int tid = threadIdx.x;
  int widx = tid>>6;
  int lane = tid & 63;
  int bx = blockIdx.x;
  if(bx >= 96){
    proj_wave(WF, X, Y, (bx-96)*4 + widx, lane);
    return;
  }
  table_wave(WF, TT, bx*4 + widx, lane, Hb[widx]);
}

__global__ __launch_bounds__(512, 8) void k_iter(const u32x2* __restrict__ desc,
                                                 const u32* __restrict__ CNT,
                                                 const u32x2* __restrict__ TT,
                                                 const float* __restrict__ Yr,
                                                 float* __restrict__ X,
                                                 float* __restrict__ Yw,
                                                 const u16* __restrict__ f2of,
                                                 const u16* __restrict__ denf,
                                                 const u16* __restrict__ in2fN,
                                                 const void* __restrict__ f2ob,
                                                 const void* __restrict__ denb,
                                                 const void* __restrict__ nmask,
                                                 void* __restrict__ OUT,
                                                 int last, int iidx){
  __shared__ __align__(16) float AGGs[16][132];
  __shared__ __align__(16) u16 Tb[16][136];
  __shared__ __align__(16) u16 Xw[16][136];
  int isbf = probe_bf(nmask);
  iter_body(desc, CNT, TT, Yr, X, Yw, f2of, denf, in2fN, f2ob, denb,
            OUT, last, iidx, isbf,
            blockIdx.x, threadIdx.x>>6, threadIdx.x&63, AGGs, Tb, Xw);
}

// ---------------------------------------------------------------------------
extern "C" void kernel_launch(void* const* d_in, const int* in_sizes, int n_in,
                              void* d_out, int out_size, void* d_ws, size_t ws_size,
                              hipStream_t stream){
  const void* pos   = d_in[0];
  const void* cell  = d_in[1];
  const void* cello = d_in[2];
  const void* nmask = d_in[3];
  // d_in[4] atom_mask: unused by the output
  const void* emb   = d_in[5];
  const void* fw1   = d_in[6];
  const void* fb1   = d_in[7];
  const void* fw2   = d_in[8];
  const void* fb2   = d_in[9];
  const void* in2f  = d_in[10];
  const void* f2o   = d_in[11];
  const void* f2ob  = d_in[12];
  const void* den   = d_in[13];
  const void* denb  = d_in[14];
  const int* z      = (const int*)d_in[15];
  const int* nbrs   = (const int*)d_in[16];

  char* ws = (char*)d_ws;
  float* X    = (float*)(ws);                 //  4 MB fp32 features
  float* Y    = (float*)(ws +  4194304);      //  4 MB projected features (ping)
  float* Y2   = (float*)(ws +  8388608);      //  4 MB projected features (pong)
  u32x2* DESC = (u32x2*)(ws + 12582912);      //  4 MB pair descriptors
  u16*   WF   = (u16*)  (ws + 16777216);      // 432 KB weight B-frags
  u32x2* TT   = (u32x2*)(ws + 17301504);      //  3 MB interleaved knot-pair table
  u32*   CNT  = (u32*)  (ws + 20447232);      // 32 KB per-atom active counts

  k_setup<<<3180, 256, 0, stream>>>(pos, cell, cello, nmask, emb,
                                    fw1, fb1, fw2, fb2, in2f, f2o, den,
                                    z, nbrs, X, DESC, CNT, WF);

  // Cooperative 3-in-1 path; fall back to R8's split dispatches on rejection.
  {
    void* desc_p = (void*)DESC; void* cnt_p = (void*)CNT; void* tt_p = (void*)TT;
    void* y_p = (void*)Y; void* y2_p = (void*)Y2; void* x_p = (void*)X;
    void* wf_p = (void*)WF; void* f2ob_p = (void*)f2ob; void* denb_p = (void*)denb;
    void* nm_p = (void*)nmask; void* out_p = d_out;
    void* args[11] = {&desc_p, &cnt_p, &tt_p, &y_p, &y2_p, &x_p, &wf_p,
                      &f2ob_p, &denb_p, &nm_p, &out_p};
    hipError_t e = hipLaunchCooperativeKernel((const void*)k_coop,
                                              dim3(1024), dim3(512),
                                              args, 0, stream);
    if(e != hipSuccess){
      k_mid<<<224, 256, 0, stream>>>(WF, TT, X, Y);
      for(int i=0;i<3;i++){
        const u16* base = WF + (size_t)i*WF_STRIDE;
        const u16* in2fN = (i<2) ? (WF + (size_t)(i+1)*WF_STRIDE + WF_IN2F) : WF;
        const float* Yrd = (i&1) ? Y2 : Y;
        float*       Ywr = (i&1) ? Y  : Y2;
        k_iter<<<1024, 512, 0, stream>>>(DESC, CNT, TT + (size_t)i*NKNOT*64,
                                         Yrd, X, Ywr,
                                         base + WF_F2O, base + WF_DEN, in2fN,
                                         f2ob, denb, nmask,
                                         d_out, (i==2) ? 1 : 0, i);
      }
    }
  }
}

// Round 12
// 161.974 us; speedup vs baseline: 3.5199x; 3.5199x over previous
//
#include <hip/hip_runtime.h>

typedef __attribute__((ext_vector_type(8))) short bf16x8;
typedef __attribute__((ext_vector_type(4))) float f32x4;
typedef __attribute__((ext_vector_type(2))) unsigned int u32x2;
typedef __attribute__((ext_vector_type(4))) unsigned int u32x4;
typedef __attribute__((ext_vector_type(2))) __bf16 bf16x2t;
typedef unsigned short u16;
typedef unsigned int u32;
typedef unsigned long long u64;

#define DI __device__ __forceinline__

// Problem constants: B=8, A=1024, NB=64, NAB=NF=128, NG=25, NI=3
#define NKNOT 2048

DI float b2f(u16 u){ union{u32 i; float f;} v; v.i = ((u32)u)<<16; return v.f; }
DI float asf(u32 u){ union{u32 i; float f;} v; v.i = u; return v.f; }
DI u16 f2b(float f){ union{float f; u32 i;} v; v.f=f; u32 u=v.i;
                     return (u16)((u + 0x7fffu + ((u>>16)&1u))>>16); }
DI u32 pk2(float lo, float hi){
#if __has_builtin(__builtin_amdgcn_cvt_pk_bf16_f32)
  bf16x2t h = __builtin_amdgcn_cvt_pk_bf16_f32(lo, hi);
  u32 d; __builtin_memcpy(&d, &h, 4); return d;
#else
  return (u32)f2b(lo) | ((u32)f2b(hi)<<16);
#endif
}
DI float fexp2(float x){
#if __has_builtin(__builtin_amdgcn_exp2f)
  return __builtin_amdgcn_exp2f(x);
#else
  return __expf(x*0.6931471805599453f);
#endif
}
DI float flog2(float x){
#if __has_builtin(__builtin_amdgcn_logf)
  return __builtin_amdgcn_logf(x);
#else
  return __logf(x)*1.4426950408889634f;
#endif
}
DI float ldin(const void* p, size_t i, int isbf){
  return isbf ? b2f(((const u16*)p)[i]) : ((const float*)p)[i];
}
DI f32x4 ldin4(const void* p, size_t i, int isbf){
  if(isbf){
    u32x2 d = *(const u32x2*)((const u16*)p + i);
    f32x4 r;
    r[0] = b2f((u16)(d[0]&0xffff)); r[1] = b2f((u16)(d[0]>>16));
    r[2] = b2f((u16)(d[1]&0xffff)); r[3] = b2f((u16)(d[1]>>16));
    return r;
  }
  return *(const f32x4*)((const float*)p + i);
}
DI int probe_bf(const void* nmask){ return ((const u16*)nmask)[0] == 0x3F80u; }

DI f32x4 mfma16(bf16x8 a, bf16x8 b, f32x4 c){
  return __builtin_amdgcn_mfma_f32_16x16x32_bf16(a,b,c,0,0,0);
}
DI bf16x8 ldfragA_f32(const float* p){
  f32x4 a = ((const f32x4*)p)[0], b = ((const f32x4*)p)[1];
  union{ u32 d[4]; bf16x8 v; } u;
  u.d[0]=pk2(a[0],a[1]); u.d[1]=pk2(a[2],a[3]);
  u.d[2]=pk2(b[0],b[1]); u.d[3]=pk2(b[2],b[3]);
  return u.v;
}
DI float sspf(float x){ return __logf(1.f + __expf(x)) - 0.6931471805599453f; }

// WF layout per interaction (u16 offsets; frag = 512 u16):
//   in2f frags off 24576 | f2o off 40960 | dense off 57344
// (fw1/fw2 regions unused: table blocks self-build from raw weights)
#define WF_STRIDE 73728
#define WF_IN2F   24576
#define WF_F2O    40960
#define WF_DEN    57344

// Block ranges in the merged setup kernel (slow blocks FIRST so they start
// at t=0 and overlap the wide embed/desc phases instead of forming a tail):
//   [0,96)       table: TT from raw fw1/fb1/fw2/fb2 (hoisted-load self-build)
//   [96,224)     proj:  Y = emb[z] @ in2f[0] (hoisted-load self-build)
//   [224,1248)   embed: X = emb[z]
//   [1248,3296)  dist -> desc (ballot-compacted) + CNT
//   [3296,3368)  wfrag: in2f/f2o/dense B-frags for k_iter
__global__ __launch_bounds__(256) void k_setup(const void* __restrict__ pos,
                                               const void* __restrict__ cell,
                                               const void* __restrict__ cello,
                                               const void* __restrict__ nmask,
                                               const void* __restrict__ emb,
                                               const void* __restrict__ fw1,
                                               const void* __restrict__ fb1,
                                               const void* __restrict__ fw2,
                                               const void* __restrict__ fb2,
                                               const void* __restrict__ in2f,
                                               const void* __restrict__ f2o,
                                               const void* __restrict__ den,
                                               const int* __restrict__ z,
                                               const int* __restrict__ nbrs,
                                               float* __restrict__ X,
                                               u32x2* __restrict__ DESC,
                                               u32* __restrict__ CNT,
                                               u16* __restrict__ WF,
                                               u32x2* __restrict__ TT,
                                               float* __restrict__ Y){
  __shared__ __align__(16) u16 Hb[4][16][168];
  int isbf = probe_bf(nmask);
  int bx = blockIdx.x, tid = threadIdx.x;
  int widx = tid>>6;
  int lane = tid & 63;
  int q = lane>>4, l15 = lane&15;

  if(bx < 96){
    // ---- table: self-build fw1/fw2 frags with HOISTED loads ----
    int wid = bx*4 + widx;           // 0..383
    int i  = wid>>7;
    int kb = (wid&127)*16;
    u16 (*H)[168] = Hb[widx];

    const float width = 5.0f/24.0f;
    const float c2 = (-0.5f/(width*width))*1.4426950408889634f;
    const float l2e = 1.4426950408889634f;
    float r = (float)(kb + l15) * (5.0f/(float)(NKNOT-1));

    float gv[8];
    #pragma unroll
    for(int j=0;j<8;j++){
      int k = q*8+j;
      if(k < 25){ float t = fmaf(-width,(float)k,r); gv[j] = fexp2(c2*t*t); }
      else gv[j] = (k==25) ? 1.f : 0.f;
    }
    union{ u32 d[4]; bf16x8 v; } afu;
    afu.d[0]=pk2(gv[0],gv[1]); afu.d[1]=pk2(gv[2],gv[3]);
    afu.d[2]=pk2(gv[4],gv[5]); afu.d[3]=pk2(gv[6],gv[7]);
    bf16x8 af = afu.v;

    f32x4 acc[8];
    // fw1 pass: rows k=q*8+j (<25 -> fw1*log2e, ==25 -> fb1*log2e, else 0)
    #pragma unroll
    for(int th=0; th<2; ++th){
      float v[4][8];
      #pragma unroll
      for(int tt=0;tt<4;tt++){
        int c = (th*4+tt)*16 + l15;
        #pragma unroll
        for(int j=0;j<8;j++){
          int k = q*8+j;
          float x;
          if(k < 25)      x = ldin(fw1, (size_t)i*3200 + (size_t)k*128 + c, isbf);
          else if(k==25)  x = ldin(fb1, (size_t)i*128 + c, isbf);
          else            x = 0.f;
          v[tt][j] = x * l2e;
        }
      }
      #pragma unroll
      for(int tt=0;tt<4;tt++){
        union{ u32 d[4]; bf16x8 w; } wu;
        wu.d[0]=pk2(v[tt][0],v[tt][1]); wu.d[1]=pk2(v[tt][2],v[tt][3]);
        wu.d[2]=pk2(v[tt][4],v[tt][5]); wu.d[3]=pk2(v[tt][6],v[tt][7]);
        acc[th*4+tt] = mfma16(wu.w, af, (f32x4){0.f,0.f,0.f,0.f});
      }
    }
    const float ln2 = 0.69314718055994531f;
    #pragma unroll
    for(int t=0;t<8;t++){
      float h0 = fmaf(flog2(1.f+fexp2(acc[t][0])), ln2, -ln2);
      float h1 = fmaf(flog2(1.f+fexp2(acc[t][1])), ln2, -ln2);
      float h2 = fmaf(flog2(1.f+fexp2(acc[t][2])), ln2, -ln2);
      float h3 = fmaf(flog2(1.f+fexp2(acc[t][3])), ln2, -ln2);
      u32x2 d; d[0]=pk2(h0,h1); d[1]=pk2(h2,h3);
      *(u32x2*)(&H[l15][t*16 + q*4]) = d;
    }
    { // bias block cols 128..159: col128 = 1.0 (adds fb2), rest 0
      u32x2 zb; zb[0] = (q==0) ? pk2(1.f, 0.f) : 0u; zb[1] = 0u;
      *(u32x2*)(&H[l15][128 + q*4]) = zb;
      u32x2 zz; zz[0]=0u; zz[1]=0u;
      *(u32x2*)(&H[l15][144 + q*4]) = zz;
    }
    #pragma unroll
    for(int t=0;t<8;t++) acc[t] = (f32x4){0.f,0.f,0.f,0.f};
    // fw2 pass: rows k=kk*32+q*8+j (<128 -> fw2, ==128 -> fb2, else 0)
    #pragma unroll
    for(int kk=0;kk<5;kk++){
      bf16x8 a2 = *(const bf16x8*)(&H[l15][kk*32 + q*8]);
      #pragma unroll
      for(int th=0; th<2; ++th){
        float v[4][8];
        #pragma unroll
        for(int tt=0;tt<4;tt++){
          int c = (th*4+tt)*16 + l15;
          #pragma unroll
          for(int j=0;j<8;j++){
            int k = kk*32 + q*8 + j;
            float x;
            if(k < 128)      x = ldin(fw2, (size_t)i*16384 + (size_t)k*128 + c, isbf);
            else if(k==128)  x = ldin(fb2, (size_t)i*128 + c, isbf);
            else             x = 0.f;
            v[tt][j] = x;
          }
        }
        #pragma unroll
        for(int tt=0;tt<4;tt++){
          union{ u32 d[4]; bf16x8 w; } wu;
          wu.d[0]=pk2(v[tt][0],v[tt][1]); wu.d[1]=pk2(v[tt][2],v[tt][3]);
          wu.d[2]=pk2(v[tt][4],v[tt][5]); wu.d[3]=pk2(v[tt][6],v[tt][7]);
          acc[th*4+tt] = mfma16(a2, wu.w, acc[th*4+tt]);
        }
      }
    }
    // store interleaved: row -> TT[row].slot0, TT[row-1].slot1
    {
      u32x2* ttb = TT + (size_t)i*NKNOT*64;
      int row = kb + l15;
      #pragma unroll
      for(int t=0;t<8;t++){
        u32 d0 = pk2(acc[t][0],acc[t][1]);
        u32 d1 = pk2(acc[t][2],acc[t][3]);
        int l = t*8 + q*2;
        ((u32*)&ttb[(size_t)row*64 + l    ])[0] = d0;
        ((u32*)&ttb[(size_t)row*64 + l + 1])[0] = d1;
        if(row > 0){
          ((u32*)&ttb[(size_t)(row-1)*64 + l    ])[1] = d0;
          ((u32*)&ttb[(size_t)(row-1)*64 + l + 1])[1] = d1;
        }
      }
    }
    return;
  }
  if(bx < 224){
    // ---- proj: y0 = emb[z] @ in2f[0], hoisted-load self-build ----
    int wid2 = (bx-96)*4 + widx;     // 0..511
    int row0 = wid2*16;
    int zr = z[row0 + l15];
    f32x4 acc[8];
    #pragma unroll
    for(int t=0;t<8;t++) acc[t] = (f32x4){0.f,0.f,0.f,0.f};
    #pragma unroll
    for(int kk=0;kk<4;kk++){
      bf16x8 xf;
      if(isbf) xf = *(const bf16x8*)((const u16*)emb + (size_t)zr*128 + kk*32 + q*8);
      else     xf = ldfragA_f32((const float*)emb + (size_t)zr*128 + kk*32 + q*8);
      #pragma unroll
      for(int th=0; th<2; ++th){
        float v[4][8];
        #pragma unroll
        for(int tt=0;tt<4;tt++){
          int c = (th*4+tt)*16 + l15;
          #pragma unroll
          for(int j=0;j<8;j++)
            v[tt][j] = ldin(in2f, (size_t)(kk*32+q*8+j)*128 + c, isbf);
        }
        #pragma unroll
        for(int tt=0;tt<4;tt++){
          union{ u32 d[4]; bf16x8 w; } wu;
          wu.d[0]=pk2(v[tt][0],v[tt][1]); wu.d[1]=pk2(v[tt][2],v[tt][3]);
          wu.d[2]=pk2(v[tt][4],v[tt][5]); wu.d[3]=pk2(v[tt][6],v[tt][7]);
          acc[th*4+tt] = mfma16(wu.w, xf, acc[th*4+tt]);
        }
      }
    }
    #pragma unroll
    for(int t=0;t<8;t++)
      *(f32x4*)(Y + (size_t)(row0+l15)*128 + t*16 + q*4) = acc[t];
    return;
  }
  if(bx < 1248){
    int idx = (bx-224)*256 + tid;              // < 8192*32
    int a = idx>>5, f4 = (idx&31)*4;
    f32x4 e = ldin4(emb, (size_t)z[a]*128 + f4, isbf);
    *(f32x4*)(X + (size_t)a*128 + f4) = e;
    return;
  }
  if(bx < 3296){
    int pairIdx = (bx-1248)*256 + tid;         // < 8192*64
    int atom = pairIdx>>6;
    int b = atom>>10;
    int nb = nbrs[pairIdx];
    int jrow = (b<<10) + nb;
    float pi0=ldin(pos,atom*3+0,isbf), pi1=ldin(pos,atom*3+1,isbf), pi2=ldin(pos,atom*3+2,isbf);
    float pj0=ldin(pos,jrow*3+0,isbf), pj1=ldin(pos,jrow*3+1,isbf), pj2=ldin(pos,jrow*3+2,isbf);
    float co0=ldin(cello,(size_t)pairIdx*3+0,isbf),
          co1=ldin(cello,(size_t)pairIdx*3+1,isbf),
          co2=ldin(cello,(size_t)pairIdx*3+2,isbf);
    size_t cb = (size_t)b*9;
    pj0 += co0*ldin(cell,cb+0,isbf) + co1*ldin(cell,cb+3,isbf) + co2*ldin(cell,cb+6,isbf);
    pj1 += co0*ldin(cell,cb+1,isbf) + co1*ldin(cell,cb+4,isbf) + co2*ldin(cell,cb+7,isbf);
    pj2 += co0*ldin(cell,cb+2,isbf) + co1*ldin(cell,cb+5,isbf) + co2*ldin(cell,cb+8,isbf);
    float d0 = pj0-pi0, d1 = pj1-pi1, d2 = pj2-pi2;
    float dd = d0*d0 + d1*d1 + d2*d2;
    float m  = ldin(nmask,pairIdx,isbf);
    float r  = sqrtf(m>0.f ? dd : 1.f) * m;
    float c  = 0.5f*(__cosf(r*3.14159265358979f/5.f)+1.f) * ((r<5.f)?1.f:0.f) * m;
    float s  = r * ((float)(NKNOT-1)/5.0f);
    int   k  = (int)s; if(k > NKNOT-2) k = NKNOT-2;
    float fr = s - (float)k;
    float a0 = c*(1.f-fr), a1 = c*fr;
    union{ _Float16 h[2]; u32 u; } pa;
    pa.h[0] = (_Float16)a0; pa.h[1] = (_Float16)a1;
    // ballot-compact: active pairs -> [0,cnt), zero-descs -> [cnt,64)
    int act = (c > 0.f);
    u64 bal = __ballot(act);
    u64 below = bal & ((1ULL<<lane)-1ULL);
    int cnt = (int)__popcll(bal);
    int apre = (int)__popcll(below);
    int pos_ = act ? apre : (cnt + (lane - apre));
    u32x2 dsc;
    if(act){ dsc[0] = pa.u; dsc[1] = (u32)k | ((u32)nb<<16); }
    else   { dsc[0] = 0u;   dsc[1] = 0u; }
    DESC[(size_t)atom*64 + pos_] = dsc;
    if(lane == 0) CNT[atom] = (u32)cnt;
    return;
  }
  // ---- wfrag: wid in [0,288) = 3 interactions x {in2f,f2o,den} x 32 frags
  {
    int wid = (bx-3296)*4 + widx;
    int i = wid/96, r = wid%96;
    int mat = r>>5, kk = (r>>3)&3, t = r&7;
    const void* src; int off;
    switch(mat){
      case 0:  src = in2f; off=WF_IN2F; break;
      case 1:  src = f2o;  off=WF_F2O;  break;
      default: src = den;  off=WF_DEN;  break;
    }
    size_t sbase = (size_t)i*16384;
    int c = t*16 + l15;
    bf16x8 frag;
    #pragma unroll
    for(int j=0;j<8;j++){
      int k = kk*32 + q*8 + j;
      frag[j] = (short)f2b(ldin(src, sbase + (size_t)k*128 + c, isbf));
    }
    *(bf16x8*)(WF + (size_t)i*WF_STRIDE + off + ((kk*8+t)*64 + lane)*8) = frag;
  }
}

// ---------------------------------------------------------------------------
// Fused iteration (byte-identical to R8): half-wave gather over compacted
// active pairs; 512 thr = 8 waves = 8 atoms/block; grid 1024 = 4 blocks/CU.
__global__ __launch_bounds__(512, 8) void k_iter(const u32x2* __restrict__ desc,
                                                 const u32* __restrict__ CNT,
                                                 const u32x2* __restrict__ TT,
                                                 const float* __restrict__ Yr,
                                                 float* __restrict__ X,
                                                 float* __restrict__ Yw,
                                                 const u16* __restrict__ f2of,
                                                 const u16* __restrict__ denf,
                                                 const u16* __restrict__ in2fN,
                                                 const void* __restrict__ f2ob,
                                                 const void* __restrict__ denb,
                                                 const void* __restrict__ nmask,
                                                 void* __restrict__ OUT,
                                                 int last, int iidx){
  __shared__ __align__(16) float AGGs[16][132];
  __shared__ __align__(16) u16 Tb[16][136];
  __shared__ __align__(16) u16 Xw[16][136];
  int isbf = probe_bf(nmask);
  int widx = threadIdx.x>>6;        // 0..7
  int lane = threadIdx.x & 63;
  int q = lane>>4, l15 = lane&15;
  int bid = blockIdx.x;
  int row0 = (bid & 7)*1024 + (bid >> 3)*8;   // 8 atoms/block, batch = bid%8

  // ---- Phase 1: CFConv over active pairs, half-wave per pair.
  {
    int atom = row0 + widx;
    int cnt = (int)__builtin_amdgcn_readfirstlane(CNT[atom]);
    int ng  = (cnt + 3) >> 2;                    // chunks of 4 pairs
    u32x2 dsc = desc[(size_t)atom*64 + lane];    // lane p holds desc of slot p
    const char* Yb = (const char*)(Yr + (size_t)(atom & ~1023)*128);
    const char* Tc = (const char*)TT;
    int h   = lane>>5;                            // half index: pair parity
    int j32 = lane&31;                            // filters 4*j32 .. 4*j32+3
    int boff = j32<<4;                            // 16 B per lane
    f32x4 acc4 = (f32x4){0.f,0.f,0.f,0.f};
    #pragma unroll 1
    for(int g=0; g<ng; ++g){                      // 4 pairs per g (2 load steps)
      u32 cu[2]; u32x4 tt[2]; f32x4 yv[2];
      #pragma unroll
      for(int s=0; s<2; ++s){
        int p0 = g*4 + s*2;
        u32 d1a = __builtin_amdgcn_readlane(dsc[1], p0);
        u32 d1b = __builtin_amdgcn_readlane(dsc[1], p0+1);
        u32 d0a = __builtin_amdgcn_readlane(dsc[0], p0);
        u32 d0b = __builtin_amdgcn_readlane(dsc[0], p0+1);
        u32 d1 = h ? d1b : d1a;
        cu[s]  = h ? d0b : d0a;
        u32 krow = d1 & 0xffffu;
        u32 nbr  = d1 >> 16;
        tt[s] = *(const u32x4*)(Tc + ((size_t)krow<<9) + boff);
        yv[s] = *(const f32x4*)(Yb + ((size_t)nbr<<9) + boff);
      }
      #pragma unroll
      for(int s=0; s<2; ++s){
        union{ u32 u; _Float16 hh[2]; } pa; pa.u = cu[s];
        float a0 = (float)pa.hh[0], a1 = (float)pa.hh[1];
        float w0 = fmaf(a1, asf(tt[s][1]<<16),          a0*asf(tt[s][0]<<16));
        float w1 = fmaf(a1, asf(tt[s][1]&0xffff0000u),  a0*asf(tt[s][0]&0xffff0000u));
        float w2 = fmaf(a1, asf(tt[s][3]<<16),          a0*asf(tt[s][2]<<16));
        float w3 = fmaf(a1, asf(tt[s][3]&0xffff0000u),  a0*asf(tt[s][2]&0xffff0000u));
        acc4[0] = fmaf(w0, yv[s][0], acc4[0]);
        acc4[1] = fmaf(w1, yv[s][1], acc4[1]);
        acc4[2] = fmaf(w2, yv[s][2], acc4[2]);
        acc4[3] = fmaf(w3, yv[s][3], acc4[3]);
      }
    }
    *(f32x4*)(&AGGs[widx + 8*h][j32*4]) = acc4;   // partials: rows a / a+8
  }
  __syncthreads();

  // ---- Phase 2: v = ssp(agg @ f2out + b); t = widx; merge halves via shfl.
  {
    int t = widx;
    f32x4 acc = (f32x4){0.f,0.f,0.f,0.f};
    #pragma unroll
    for(int kk=0;kk<4;kk++){
      bf16x8 gf = ldfragA_f32(&AGGs[l15][kk*32 + q*8]);
      bf16x8 wv = *(const bf16x8*)(f2of + ((kk*8+t)*64 + lane)*8);
      acc = mfma16(wv, gf, acc);
    }
    #pragma unroll
    for(int r=0;r<4;r++) acc[r] += __shfl_xor(acc[r], 8);
    f32x4 bv = ldin4(f2ob, (size_t)iidx*128 + t*16 + q*4, isbf);
    u32x2 d;
    d[0] = pk2(sspf(acc[0]+bv[0]), sspf(acc[1]+bv[1]));
    d[1] = pk2(sspf(acc[2]+bv[2]), sspf(acc[3]+bv[3]));
    *(u32x2*)(&Tb[l15][t*16 + q*4]) = d;   // rows 8-15 duplicate rows 0-7
  }
  __syncthreads();

  // ---- Phase 2b: dense @ + bias + X residual; stores guarded to l15<8.
  {
    int t = widx;
    f32x4 acc = (f32x4){0.f,0.f,0.f,0.f};
    #pragma unroll
    for(int kk=0;kk<4;kk++){
      bf16x8 tf = *(const bf16x8*)(&Tb[l15][kk*32 + q*8]);
      bf16x8 wv = *(const bf16x8*)(denf + ((kk*8+t)*64 + lane)*8);
      acc = mfma16(wv, tf, acc);
    }
    size_t idx = (size_t)(row0+l15)*128 + t*16 + q*4;
    f32x4 bv = ldin4(denb, (size_t)iidx*128 + t*16 + q*4, isbf);
    f32x4 xv = *(const f32x4*)(X + idx);
    f32x4 xn;
    #pragma unroll
    for(int r=0;r<4;r++) xn[r] = xv[r] + acc[r] + bv[r];
    if(l15 < 8){
      *(f32x4*)(X + idx) = xn;
      if(last){
        if(isbf){
          u32x2 o; o[0]=pk2(xn[0],xn[1]); o[1]=pk2(xn[2],xn[3]);
          *(u32x2*)((u16*)OUT + idx) = o;
        } else {
          *(f32x4*)((float*)OUT + idx) = xn;
        }
      }
    }
    if(!last){
      u32x2 d; d[0]=pk2(xn[0],xn[1]); d[1]=pk2(xn[2],xn[3]);
      *(u32x2*)(&Xw[l15][t*16 + q*4]) = d;
    }
  }
  if(!last){
    __syncthreads();
    // ---- Phase 3: y_next = x_new @ in2f_next (other Y buffer); l15<8 stores.
    {
      int t = widx;
      f32x4 acc = (f32x4){0.f,0.f,0.f,0.f};
      #pragma unroll
      for(int kk=0;kk<4;kk++){
        bf16x8 xf = *(const bf16x8*)(&Xw[l15][kk*32 + q*8]);
        bf16x8 wv = *(const bf16x8*)(in2fN + ((kk*8+t)*64 + lane)*8);
        acc = mfma16(wv, xf, acc);
      }
      if(l15 < 8)
        *(f32x4*)(Yw + (size_t)(row0+l15)*128 + t*16 + q*4) = acc;
    }
  }
}

// ---------------------------------------------------------------------------
extern "C" void kernel_launch(void* const* d_in, const int* in_sizes, int n_in,
                              void* d_out, int out_size, void* d_ws, size_t ws_size,
                              hipStream_t stream){
  const void* pos   = d_in[0];
  const void* cell  = d_in[1];
  const void* cello = d_in[2];
  const void* nmask = d_in[3];
  // d_in[4] atom_mask: unused by the output
  const void* emb   = d_in[5];
  const void* fw1   = d_in[6];
  const void* fb1   = d_in[7];
  const void* fw2   = d_in[8];
  const void* fb2   = d_in[9];
  const void* in2f  = d_in[10];
  const void* f2o   = d_in[11];
  const void* f2ob  = d_in[12];
  const void* den   = d_in[13];
  const void* denb  = d_in[14];
  const int* z      = (const int*)d_in[15];
  const int* nbrs   = (const int*)d_in[16];

  char* ws = (char*)d_ws;
  float* X    = (float*)(ws);                 //  4 MB fp32 features
  float* Y    = (float*)(ws +  4194304);      //  4 MB projected features (ping)
  float* Y2   = (float*)(ws +  8388608);      //  4 MB projected features (pong)
  u32x2* DESC = (u32x2*)(ws + 12582912);      //  4 MB pair descriptors
  u16*   WF   = (u16*)  (ws + 16777216);      // 432 KB weight B-frags
  u32x2* TT   = (u32x2*)(ws + 17301504);      //  3 MB interleaved knot-pair table
  u32*   CNT  = (u32*)  (ws + 20447232);      // 32 KB per-atom active counts

  k_setup<<<3368, 256, 0, stream>>>(pos, cell, cello, nmask, emb,
                                    fw1, fb1, fw2, fb2, in2f, f2o, den,
                                    z, nbrs, X, DESC, CNT, WF, TT, Y);

  for(int i=0;i<3;i++){
    const u16* base = WF + (size_t)i*WF_STRIDE;
    const u16* in2fN = (i<2) ? (WF + (size_t)(i+1)*WF_STRIDE + WF_IN2F) : WF;
    const float* Yrd = (i&1) ? Y2 : Y;
    float*       Ywr = (i&1) ? Y  : Y2;
    k_iter<<<1024, 512, 0, stream>>>(DESC, CNT, TT + (size_t)i*NKNOT*64, Yrd, X, Ywr,
                                     base + WF_F2O, base + WF_DEN, in2fN,
                                     f2ob, denb, nmask,
                                     d_out, (i==2) ? 1 : 0, i);
  }
}